// Round 15
// baseline (117.454 us; speedup 1.0000x reference)
//
#include <hip/hip_runtime.h>
#include <math.h>

// CircleLoss, symmetric-triangle bf16-MFMA, chunked column tiles.
//   R15: block = (RT, chunk of 4 CTs), grid (16,64), invalid blocks exit.
//   A staged once per block; B per tile; row partials accumulate in REGISTERS
//   across the chunk -> transpose-reduce once per block (packed u32 tbuf
//   aliased over dead B tile). Col partials per tile (shuffle reduce).
//   Slots: col = 2RT+wr (0..127), row = 128+2c+wc (128..159); for row g
//   (RTg=g>>7, c0=RTg>>2) written slots are exactly {0..2RTg-1} u
//   {128+2c0..159}; rowloss iterates exactly those. No atomics, no memset.
//   Numerics: u-form epilogue, DIRECT (P,N) accumulation (no T-P cancel).
// ws: 2MB featsN + 5.25MB partial[160][B] + 1KB blocksum = 7.25MB (<8MB).

#define DIM 128
#define NSLOT 160
typedef short bf16x8 __attribute__((ext_vector_type(8)));
typedef float f32x4 __attribute__((ext_vector_type(4)));

#if __has_builtin(__builtin_amdgcn_exp2f)
#define EXP2F __builtin_amdgcn_exp2f
#else
#define EXP2F exp2f
#endif

__device__ __forceinline__ unsigned short f2bf(float f) {
    unsigned int b = __float_as_uint(f);
    unsigned int r = (b + 0x7FFFu + ((b >> 16) & 1u)) >> 16;   // RN-even
    return (unsigned short)r;
}
__device__ __forceinline__ unsigned int packPN(float p, float n) {
    return (unsigned int)f2bf(p) | ((unsigned int)f2bf(n) << 16);
}

// ---------------- Kernel 1: normalize + quantize ----------------
__global__ void prep_kernel(const float* __restrict__ feats,
                            unsigned int* __restrict__ featsN, int B) {
    int wave = (blockIdx.x * blockDim.x + threadIdx.x) >> 6;
    int lane = threadIdx.x & 63;
    if (wave >= B) return;
    const float2* rp = (const float2*)(feats + (size_t)wave * DIM);
    float2 v = rp[lane];
    float s = v.x * v.x + v.y * v.y;
#pragma unroll
    for (int off = 32; off; off >>= 1) s += __shfl_xor(s, off);
    float inv = rsqrtf(s);
    featsN[(size_t)wave * 64 + lane] =
        (unsigned int)f2bf(v.x * inv) | ((unsigned int)f2bf(v.y * inv) << 16);
}

// ---------------- Kernel 2: chunked triangular MFMA + masked exp ----------------
// grid (16 chunks, 64 RTs), 256 threads (4 waves, 2x2 of 64x64 per tile).
__global__ __launch_bounds__(256, 2) void circle_main_kernel(
    const unsigned short* __restrict__ featsN, const int* __restrict__ labels,
    unsigned int* __restrict__ partial, int B) {
    const int ch = blockIdx.x;          // chunk: CTs [4ch, 4ch+4)
    const int RT = blockIdx.y;          // row tile
    const int c0 = RT >> 2;
    if (ch < c0) return;                // block has no CT >= RT
    const int ctStart = (RT > ch * 4) ? RT : ch * 4;
    const int ctEnd = ch * 4 + 4;

    __shared__ unsigned char smem[65536] __attribute__((aligned(16)));
    unsigned char* Al = smem;
    unsigned char* Bl = smem + 32768;
    unsigned int* tbuf = (unsigned int*)(smem + 32768);  // aliases Bl (dead at end)

    const int tid = threadIdx.x;
    const int lane = tid & 63;
    const int wv = tid >> 6;
    const int wr = wv >> 1, wc = wv & 1;
    const int lg = lane >> 4;
    const int l15 = lane & 15;
    const int rowbase = RT * 128 + wr * 64;

    // ---- stage A (RT rows), 4-bit XOR swizzle (once per block) ----
    {
        const int r0 = tid >> 4, cc = tid & 15;
#pragma unroll
        for (int it = 0; it < 8; ++it) {
            int row = it * 16 + r0;
            int swz = ((cc ^ (row & 15)) << 4);
            int4 va = *(const int4*)(featsN + (size_t)(RT * 128 + row) * DIM + cc * 8);
            *(int4*)(Al + row * 256 + swz) = va;
        }
    }

    int lr[4][4];
#pragma unroll
    for (int m = 0; m < 4; ++m)
#pragma unroll
        for (int r = 0; r < 4; ++r) lr[m][r] = labels[rowbase + m * 16 + lg * 4 + r];

    const float S2 = 46.166241308446828f;   // 32*log2(e)
    const float C2 = -23.083120654223414f;  // -0.5*S2

    float rP[4][4], rN[4][4];
#pragma unroll
    for (int m = 0; m < 4; ++m)
#pragma unroll
        for (int r = 0; r < 4; ++r) { rP[m][r] = 0.f; rN[m][r] = 0.f; }

    for (int CT = ctStart; CT < ctEnd; ++CT) {
        __syncthreads();   // A staged (1st iter) / prev B fragment reads done
        // ---- stage B (CT rows) ----
        {
            const int r0 = tid >> 4, cc = tid & 15;
#pragma unroll
            for (int it = 0; it < 8; ++it) {
                int row = it * 16 + r0;
                int swz = ((cc ^ (row & 15)) << 4);
                int4 vb = *(const int4*)(featsN + (size_t)(CT * 128 + row) * DIM + cc * 8);
                *(int4*)(Bl + row * 256 + swz) = vb;
            }
        }
        __syncthreads();

        // ---- MFMA: 64 per wave (4m x 4n x 4k) ----
        f32x4 acc[4][4];
#pragma unroll
        for (int m = 0; m < 4; ++m)
#pragma unroll
            for (int n = 0; n < 4; ++n) acc[m][n] = (f32x4){0.f, 0.f, 0.f, 0.f};
#pragma unroll
        for (int kk = 0; kk < 4; ++kk) {
            bf16x8 af[4], bfr[4];
#pragma unroll
            for (int m = 0; m < 4; ++m) {
                int row = wr * 64 + m * 16 + l15;
                af[m] = __builtin_bit_cast(bf16x8,
                    *(const int4*)(Al + row * 256 + (((kk * 4 + lg) ^ (row & 15)) << 4)));
            }
#pragma unroll
            for (int n = 0; n < 4; ++n) {
                int row = wc * 64 + n * 16 + l15;
                bfr[n] = __builtin_bit_cast(bf16x8,
                    *(const int4*)(Bl + row * 256 + (((kk * 4 + lg) ^ (row & 15)) << 4)));
            }
#pragma unroll
            for (int m = 0; m < 4; ++m)
#pragma unroll
                for (int n = 0; n < 4; ++n)
                    acc[m][n] = __builtin_amdgcn_mfma_f32_16x16x32_bf16(
                        af[m], bfr[n], acc[m][n], 0, 0, 0);
        }

        // ---- epilogue: u-form, DIRECT (P, N) accumulation ----
        const int colbase = CT * 128 + wc * 64;
        int lc[4];
#pragma unroll
        for (int n = 0; n < 4; ++n) lc[n] = labels[colbase + n * 16 + l15];

        if (CT == RT) {
            // diagonal tile: self-exclusion, no col partials
#pragma unroll
            for (int m = 0; m < 4; ++m) {
#pragma unroll
                for (int r = 0; r < 4; ++r) {
                    const int grow = rowbase + m * 16 + lg * 4 + r;
                    const int lrow = lr[m][r];
                    float psum = 0.f, nsum = 0.f;
#pragma unroll
                    for (int n = 0; n < 4; ++n) {
                        float sim = acc[m][n][r];
                        bool same = (lrow == lc[n]);
                        float u = same ? (1.25f - sim) : (sim + 0.25f);
                        float e2 = fmaxf(u, 0.f) * fmaf(S2, u, C2);
                        float v = EXP2F(e2);
                        bool self = (grow == colbase + n * 16 + l15);
                        float pv = (same && !self) ? v : 0.f;
                        float nv = same ? 0.f : v;
                        psum += pv; nsum += nv;
                    }
                    rP[m][r] += psum; rN[m][r] += nsum;
                }
            }
        } else {
            float cP[4] = {0.f, 0.f, 0.f, 0.f}, cN[4] = {0.f, 0.f, 0.f, 0.f};
#pragma unroll
            for (int m = 0; m < 4; ++m) {
#pragma unroll
                for (int r = 0; r < 4; ++r) {
                    const int lrow = lr[m][r];
                    float psum = 0.f, nsum = 0.f;
#pragma unroll
                    for (int n = 0; n < 4; ++n) {
                        float sim = acc[m][n][r];
                        bool same = (lrow == lc[n]);
                        float u = same ? (1.25f - sim) : (sim + 0.25f);
                        float e2 = fmaxf(u, 0.f) * fmaf(S2, u, C2);
                        float v = EXP2F(e2);
                        float pv = same ? v : 0.f;
                        float nv = v - pv;          // exact: pv is v or 0
                        psum += pv; nsum += nv;
                        cP[n] += pv; cN[n] += nv;
                    }
                    rP[m][r] += psum; rN[m][r] += nsum;
                }
            }
            // col partials: shuffle reduce over lane groups, slot = RT*2 + wr
#pragma unroll
            for (int n = 0; n < 4; ++n) {
                float p = cP[n], n_ = cN[n];
                p += __shfl_xor(p, 16); p += __shfl_xor(p, 32);
                n_ += __shfl_xor(n_, 16); n_ += __shfl_xor(n_, 32);
                if (lg == 0) {
                    int gcol = colbase + n * 16 + l15;
                    partial[(size_t)(RT * 2 + wr) * B + gcol] = packPN(p, n_);
                }
            }
        }
    }

    // ---- row partials: transpose-reduce once per block (tbuf aliases Bl) ----
    __syncthreads();   // all Bl fragment reads complete before reuse
    {
        unsigned int* T = tbuf + wv * 64 * 17;
#pragma unroll
        for (int m = 0; m < 4; ++m)
#pragma unroll
            for (int r = 0; r < 4; ++r)
                T[(m * 16 + lg * 4 + r) * 17 + l15] = packPN(rP[m][r], rN[m][r]);
    }
    __syncthreads();
    {
        const unsigned int* T = tbuf + wv * 64 * 17 + lane * 17;
        float p = 0.f, n_ = 0.f;
#pragma unroll
        for (int cidx = 0; cidx < 16; ++cidx) {
            unsigned int v = T[cidx];
            p += __uint_as_float(v << 16);
            n_ += __uint_as_float(v & 0xFFFF0000u);
        }
        int grow = RT * 128 + wr * 64 + lane;
        partial[(size_t)(128 + ch * 2 + wc) * B + grow] = packPN(p, n_);
    }
}

// ---------------- Kernel 3: per-row log1p(p*n), wave sums ----------------
// 128 blocks x 64 threads; row's written slots: {0..2RTg-1} u {128+2c0..159}.
__global__ void rowloss_kernel(const unsigned int* __restrict__ partial,
                               double* __restrict__ blocksum, int B) {
    int row = blockIdx.x * 64 + threadIdx.x;
    int RTg = row >> 7;
    int c0 = RTg >> 2;
    float p = 0.f, n = 0.f;
    for (int c = 0; c < 2 * RTg; ++c) {
        unsigned int v = partial[(size_t)c * B + row];
        p += __uint_as_float(v << 16);
        n += __uint_as_float(v & 0xFFFF0000u);
    }
    for (int c = 128 + 2 * c0; c < NSLOT; ++c) {
        unsigned int v = partial[(size_t)c * B + row];
        p += __uint_as_float(v << 16);
        n += __uint_as_float(v & 0xFFFF0000u);
    }
    double l = log1p((double)p * (double)n);
#pragma unroll
    for (int off = 32; off; off >>= 1) l += __shfl_xor(l, off);
    if (threadIdx.x == 0) blocksum[blockIdx.x] = l;
}

__global__ void final_kernel(const double* __restrict__ blocksum,
                             float* __restrict__ out, int nblk, int B) {
    __shared__ double sdata[128];
    int tid = threadIdx.x;
    sdata[tid] = (tid < nblk) ? blocksum[tid] : 0.0;
    __syncthreads();
    for (int s = 64; s; s >>= 1) {
        if (tid < s) sdata[tid] += sdata[tid + s];
        __syncthreads();
    }
    if (tid == 0) out[0] = (float)(sdata[0] / (double)B);
}

extern "C" void kernel_launch(void* const* d_in, const int* in_sizes, int n_in,
                              void* d_out, int out_size, void* d_ws, size_t ws_size,
                              hipStream_t stream) {
    const float* feats = (const float*)d_in[0];
    const int* labels = (const int*)d_in[1];
    float* out = (float*)d_out;
    int B = in_sizes[1];  // 8192

    // ws: featsN bf16 [B][128] (2MB) | partial u32 [160][B] (5.25MB) | blocksum (1KB)
    unsigned int* featsN = (unsigned int*)d_ws;
    size_t off1 = ((size_t)B * DIM * 2 + 255) & ~(size_t)255;
    unsigned int* partial = (unsigned int*)((char*)d_ws + off1);
    size_t off2 = off1 + (((size_t)B * NSLOT * sizeof(unsigned int) + 255) & ~(size_t)255);
    double* blocksum = (double*)((char*)d_ws + off2);

    prep_kernel<<<B / 4, 256, 0, stream>>>(feats, featsN, B);

    dim3 grid(16, 64);  // (chunk, RT); blocks with chunk < RT/4 exit early
    circle_main_kernel<<<grid, 256, 0, stream>>>((const unsigned short*)featsN,
                                                 labels, partial, B);

    int nblk = B / 64;  // 128
    rowloss_kernel<<<nblk, 64, 0, stream>>>(partial, blocksum, B);
    final_kernel<<<1, 128, 0, stream>>>(blocksum, out, nblk, B);
}

// Round 16
// 44.266 us; speedup vs baseline: 2.6534x; 2.6534x over previous
//
#include <hip/hip_runtime.h>
#include <math.h>

// CircleLoss, symmetric-triangle bf16-MFMA, 48KB LDS (B staged in halves).
//   R15 lesson: chunking can't win (per-tile cost ~8us is staging-independent);
//   tail killed it. R16 lever = occupancy: A tile 32KB + B half-tile 16KB =
//   48KB LDS -> 3 blocks/CU (was 2 @64KB). Per half: stage/bar/MFMA/epilogue;
//   acc[4][2] per half (lower VGPR). Row partials accumulate across halves ->
//   one transpose-reduce per block (tbuf aliases dead A). Col partials per half.
//   Slots (R14-validated): col = 2RT+wr, row = 2CT+wc; each (slot,row) written
//   exactly once. No atomics. u-form epilogue + DIRECT (P,N) accumulation.
// ws (256MB available): 2MB featsN + 4MB partial[128][B] + 1KB blocksum.

#define DIM 128
typedef short bf16x8 __attribute__((ext_vector_type(8)));
typedef float f32x4 __attribute__((ext_vector_type(4)));

#if __has_builtin(__builtin_amdgcn_exp2f)
#define EXP2F __builtin_amdgcn_exp2f
#else
#define EXP2F exp2f
#endif

__device__ __forceinline__ unsigned short f2bf(float f) {
    unsigned int b = __float_as_uint(f);
    unsigned int r = (b + 0x7FFFu + ((b >> 16) & 1u)) >> 16;   // RN-even
    return (unsigned short)r;
}
__device__ __forceinline__ unsigned int packPN(float p, float n) {
    return (unsigned int)f2bf(p) | ((unsigned int)f2bf(n) << 16);
}

// ---------------- Kernel 1: normalize + quantize ----------------
__global__ void prep_kernel(const float* __restrict__ feats,
                            unsigned int* __restrict__ featsN, int B) {
    int wave = (blockIdx.x * blockDim.x + threadIdx.x) >> 6;
    int lane = threadIdx.x & 63;
    if (wave >= B) return;
    const float2* rp = (const float2*)(feats + (size_t)wave * DIM);
    float2 v = rp[lane];
    float s = v.x * v.x + v.y * v.y;
#pragma unroll
    for (int off = 32; off; off >>= 1) s += __shfl_xor(s, off);
    float inv = rsqrtf(s);
    featsN[(size_t)wave * 64 + lane] =
        (unsigned int)f2bf(v.x * inv) | ((unsigned int)f2bf(v.y * inv) << 16);
}

// ---------------- Kernel 2: triangular fused MFMA + masked exp ----------------
// 2080 blocks = tile pairs (RT,CT), RT<=CT. 4 waves (2x2). B staged in 2 halves.
__global__ __launch_bounds__(256, 3) void circle_main_kernel(
    const unsigned short* __restrict__ featsN, const int* __restrict__ labels,
    unsigned int* __restrict__ partial, int B) {
    __shared__ unsigned char smem[49152] __attribute__((aligned(16)));
    unsigned char* Al = smem;                     // 32KB: A tile 128 rows
    unsigned char* Bl = smem + 32768;             // 16KB: B half-tile 64 rows
    unsigned int* tbuf = (unsigned int*)smem;     // 17408B, aliases dead Al

    // ---- unrank bid -> (RT, CT), RT <= CT (R14-validated) ----
    int bid = blockIdx.x;
    int RT = (int)((129.0 - sqrt(16641.0 - 8.0 * (double)bid)) * 0.5);
    RT = RT < 0 ? 0 : (RT > 63 ? 63 : RT);
    while (64 * RT - (RT * (RT - 1)) / 2 > bid) --RT;
    while (64 * (RT + 1) - ((RT + 1) * RT) / 2 <= bid) ++RT;
    const int CT = RT + (bid - (64 * RT - (RT * (RT - 1)) / 2));
    const bool diag = (RT == CT);

    const int tid = threadIdx.x;
    const int lane = tid & 63;
    const int wv = tid >> 6;
    const int wr = wv >> 1, wc = wv & 1;          // wave = 64 rows x 32 cols of half
    const int lg = lane >> 4;
    const int l15 = lane & 15;
    const int rowbase = RT * 128 + wr * 64;

    // ---- stage A (128 rows), 4-bit XOR swizzle ----
    {
        const int r0 = tid >> 4, cc = tid & 15;
#pragma unroll
        for (int it = 0; it < 8; ++it) {
            int row = it * 16 + r0;
            int swz = ((cc ^ r0) << 4);           // row&15 == r0
            int4 va = *(const int4*)(featsN + (size_t)(RT * 128 + row) * DIM + cc * 8);
            *(int4*)(Al + row * 256 + swz) = va;
        }
    }

    int lr[4][4];
#pragma unroll
    for (int m = 0; m < 4; ++m)
#pragma unroll
        for (int r = 0; r < 4; ++r) lr[m][r] = labels[rowbase + m * 16 + lg * 4 + r];

    const float S2 = 46.166241308446828f;   // 32*log2(e)
    const float C2 = -23.083120654223414f;  // -0.5*S2

    float rP[4][4], rN[4][4];
#pragma unroll
    for (int m = 0; m < 4; ++m)
#pragma unroll
        for (int r = 0; r < 4; ++r) { rP[m][r] = 0.f; rN[m][r] = 0.f; }

#pragma unroll
    for (int h = 0; h < 2; ++h) {
        __syncthreads();   // A staged (h=0) / prev half's B reads done (h=1)
        // ---- stage B half (64 rows) ----
        {
            const int r0 = tid >> 4, cc = tid & 15;
#pragma unroll
            for (int it = 0; it < 4; ++it) {
                int row = it * 16 + r0;
                int swz = ((cc ^ r0) << 4);
                int4 vb = *(const int4*)(featsN +
                    (size_t)(CT * 128 + h * 64 + row) * DIM + cc * 8);
                *(int4*)(Bl + row * 256 + swz) = vb;
            }
        }
        __syncthreads();

        // ---- MFMA: 32 per wave (4m x 2n x 4k) ----
        f32x4 acc[4][2];
#pragma unroll
        for (int m = 0; m < 4; ++m)
#pragma unroll
            for (int n = 0; n < 2; ++n) acc[m][n] = (f32x4){0.f, 0.f, 0.f, 0.f};
#pragma unroll
        for (int kk = 0; kk < 4; ++kk) {
            bf16x8 af[4], bfr[2];
#pragma unroll
            for (int m = 0; m < 4; ++m) {
                int row = wr * 64 + m * 16 + l15;
                af[m] = __builtin_bit_cast(bf16x8,
                    *(const int4*)(Al + row * 256 + (((kk * 4 + lg) ^ l15) << 4)));
            }
#pragma unroll
            for (int n = 0; n < 2; ++n) {
                int row = wc * 32 + n * 16 + l15;
                bfr[n] = __builtin_bit_cast(bf16x8,
                    *(const int4*)(Bl + row * 256 + (((kk * 4 + lg) ^ l15) << 4)));
            }
#pragma unroll
            for (int m = 0; m < 4; ++m)
#pragma unroll
                for (int n = 0; n < 2; ++n)
                    acc[m][n] = __builtin_amdgcn_mfma_f32_16x16x32_bf16(
                        af[m], bfr[n], acc[m][n], 0, 0, 0);
        }

        // ---- epilogue (half): u-form, DIRECT (P, N) accumulation ----
        const int colbase = CT * 128 + h * 64 + wc * 32;
        int lc[2];
#pragma unroll
        for (int n = 0; n < 2; ++n) lc[n] = labels[colbase + n * 16 + l15];

        if (diag) {
#pragma unroll
            for (int m = 0; m < 4; ++m) {
#pragma unroll
                for (int r = 0; r < 4; ++r) {
                    const int grow = rowbase + m * 16 + lg * 4 + r;
                    const int lrow = lr[m][r];
                    float psum = 0.f, nsum = 0.f;
#pragma unroll
                    for (int n = 0; n < 2; ++n) {
                        float sim = acc[m][n][r];
                        bool same = (lrow == lc[n]);
                        float u = same ? (1.25f - sim) : (sim + 0.25f);
                        float e2 = fmaxf(u, 0.f) * fmaf(S2, u, C2);
                        float v = EXP2F(e2);
                        bool self = (grow == colbase + n * 16 + l15);
                        float pv = (same && !self) ? v : 0.f;
                        float nv = same ? 0.f : v;
                        psum += pv; nsum += nv;
                    }
                    rP[m][r] += psum; rN[m][r] += nsum;
                }
            }
        } else {
            float cP[2] = {0.f, 0.f}, cN[2] = {0.f, 0.f};
#pragma unroll
            for (int m = 0; m < 4; ++m) {
#pragma unroll
                for (int r = 0; r < 4; ++r) {
                    const int lrow = lr[m][r];
                    float psum = 0.f, nsum = 0.f;
#pragma unroll
                    for (int n = 0; n < 2; ++n) {
                        float sim = acc[m][n][r];
                        bool same = (lrow == lc[n]);
                        float u = same ? (1.25f - sim) : (sim + 0.25f);
                        float e2 = fmaxf(u, 0.f) * fmaf(S2, u, C2);
                        float v = EXP2F(e2);
                        float pv = same ? v : 0.f;
                        float nv = v - pv;        // exact: pv is v or 0
                        psum += pv; nsum += nv;
                        cP[n] += pv; cN[n] += nv;
                    }
                    rP[m][r] += psum; rN[m][r] += nsum;
                }
            }
            // col partials: shuffle reduce over lane groups, slot = RT*2 + wr
#pragma unroll
            for (int n = 0; n < 2; ++n) {
                float p = cP[n], n_ = cN[n];
                p += __shfl_xor(p, 16); p += __shfl_xor(p, 32);
                n_ += __shfl_xor(n_, 16); n_ += __shfl_xor(n_, 32);
                if (lg == 0) {
                    int gcol = colbase + n * 16 + l15;
                    partial[(size_t)(RT * 2 + wr) * B + gcol] = packPN(p, n_);
                }
            }
        }
    }

    // ---- row partials: transpose-reduce once per block (tbuf aliases Al) ----
    __syncthreads();   // all Al/Bl fragment reads complete before reuse
    {
        unsigned int* T = tbuf + wv * 64 * 17;
#pragma unroll
        for (int m = 0; m < 4; ++m)
#pragma unroll
            for (int r = 0; r < 4; ++r)
                T[(m * 16 + lg * 4 + r) * 17 + l15] = packPN(rP[m][r], rN[m][r]);
    }
    __syncthreads();
    {
        const unsigned int* T = tbuf + wv * 64 * 17 + lane * 17;
        float p = 0.f, n_ = 0.f;
#pragma unroll
        for (int c = 0; c < 16; ++c) {
            unsigned int v = T[c];
            p += __uint_as_float(v << 16);
            n_ += __uint_as_float(v & 0xFFFF0000u);
        }
        int grow = RT * 128 + wr * 64 + lane;
        partial[(size_t)(CT * 2 + wc) * B + grow] = packPN(p, n_);
    }
}

// ---------------- Kernel 3: per-row log1p(p*n), wave sums ----------------
__global__ void rowloss_kernel(const unsigned int* __restrict__ partial,
                               double* __restrict__ blocksum, int B) {
    int row = blockIdx.x * 64 + threadIdx.x;
    float p = 0.f, n = 0.f;
#pragma unroll
    for (int c = 0; c < 128; ++c) {
        unsigned int v = partial[(size_t)c * B + row];
        p += __uint_as_float(v << 16);
        n += __uint_as_float(v & 0xFFFF0000u);
    }
    double l = log1p((double)p * (double)n);
#pragma unroll
    for (int off = 32; off; off >>= 1) l += __shfl_xor(l, off);
    if (threadIdx.x == 0) blocksum[blockIdx.x] = l;
}

__global__ void final_kernel(const double* __restrict__ blocksum,
                             float* __restrict__ out, int nblk, int B) {
    __shared__ double sdata[128];
    int tid = threadIdx.x;
    sdata[tid] = (tid < nblk) ? blocksum[tid] : 0.0;
    __syncthreads();
    for (int s = 64; s; s >>= 1) {
        if (tid < s) sdata[tid] += sdata[tid + s];
        __syncthreads();
    }
    if (tid == 0) out[0] = (float)(sdata[0] / (double)B);
}

extern "C" void kernel_launch(void* const* d_in, const int* in_sizes, int n_in,
                              void* d_out, int out_size, void* d_ws, size_t ws_size,
                              hipStream_t stream) {
    const float* feats = (const float*)d_in[0];
    const int* labels = (const int*)d_in[1];
    float* out = (float*)d_out;
    int B = in_sizes[1];  // 8192

    // ws: featsN bf16 [B][128] (2MB) | partial u32 [128][B] (4MB) | blocksum (1KB)
    unsigned int* featsN = (unsigned int*)d_ws;
    size_t off1 = ((size_t)B * DIM * 2 + 255) & ~(size_t)255;
    unsigned int* partial = (unsigned int*)((char*)d_ws + off1);
    size_t off2 = off1 + (((size_t)B * 128 * sizeof(unsigned int) + 255) & ~(size_t)255);
    double* blocksum = (double*)((char*)d_ws + off2);

    prep_kernel<<<B / 4, 256, 0, stream>>>(feats, featsN, B);

    int ntiles = B / 128;                      // 64
    int nblocks = ntiles * (ntiles + 1) / 2;   // 2080
    circle_main_kernel<<<nblocks, 256, 0, stream>>>((const unsigned short*)featsN,
                                                    labels, partial, B);

    int nblk = B / 64;  // 128
    rowloss_kernel<<<nblk, 64, 0, stream>>>(partial, blocksum, B);
    final_kernel<<<1, 128, 0, stream>>>(blocksum, out, nblk, B);
}